// Round 1
// baseline (127.826 us; speedup 1.0000x reference)
//
#include <hip/hip_runtime.h>

typedef unsigned short u16;
typedef unsigned int u32;
typedef __attribute__((ext_vector_type(8))) short bfrag;   // 8 x bf16 (4 VGPRs)
typedef __attribute__((ext_vector_type(4))) float f32x4;

#define S_LEN 2048
#define DMODEL 1024
#define NHQ 16
#define NHKV 4
#define HD 64
#define HALFW 128
#define ROWS 4096   // B*S

__device__ __forceinline__ u16 f2b(float f) {
  u32 x = __float_as_uint(f);
  return (u16)((x + 0x7fffu + ((x >> 16) & 1u)) >> 16);  // RNE
}

// ---------------- kernel 1: RoPE table (double precision trig) ----------------
__global__ void rope_table_k(float* __restrict__ cosT, float* __restrict__ sinT) {
  int idx = blockIdx.x * blockDim.x + threadIdx.x;  // S_LEN*32 exactly
  int s = idx >> 5, i = idx & 31;
  double inv = pow(10000.0, -(double)(2 * i) / 64.0);
  double ang = (double)s * inv;
  cosT[idx] = (float)cos(ang);
  sinT[idx] = (float)sin(ang);
}

// ---------------- kernel 2: cast x -> bf16 ----------------
__global__ void cast_x_k(const float* __restrict__ x, u16* __restrict__ xb) {
  int i = (blockIdx.x * blockDim.x + threadIdx.x) * 4;
  float4 v = *reinterpret_cast<const float4*>(x + i);
  uint2 p;
  p.x = (u32)f2b(v.x) | ((u32)f2b(v.y) << 16);
  p.y = (u32)f2b(v.z) | ((u32)f2b(v.w) << 16);
  *reinterpret_cast<uint2*>(xb + i) = p;
}

// ---------------- kernel 3: transpose-cast weight (K=1024 rows x ncols) -> (ncols x 1024) bf16
__global__ void transpose_cast_k(const float* __restrict__ src, int ncols, u16* __restrict__ dst) {
  __shared__ float tile[32][33];
  int k0 = blockIdx.x * 32, n0 = blockIdx.y * 32;
  int tx = threadIdx.x, ty = threadIdx.y;  // 32 x 8
#pragma unroll
  for (int j = 0; j < 4; ++j)
    tile[ty + 8 * j][tx] = src[(size_t)(k0 + ty + 8 * j) * ncols + n0 + tx];
  __syncthreads();
#pragma unroll
  for (int j = 0; j < 4; ++j)
    dst[(size_t)(n0 + ty + 8 * j) * 1024 + k0 + tx] = f2b(tile[tx][ty + 8 * j]);
}

// ---------------- kernel 4/7: 128x128 bf16 GEMM, C fp32. A:(M,1024) row, Bt:(N,1024) row ----------------
__global__ __launch_bounds__(256) void gemm_bt_k(const u16* __restrict__ A, const u16* __restrict__ Bt,
                                                 float* __restrict__ C, int N) {
  __shared__ u16 lds_a[128 * 32];
  __shared__ u16 lds_b[128 * 32];
  int t = threadIdx.x;
  int wave = t >> 6, lane = t & 63;
  int g = lane >> 4, col = lane & 15;
  int m0 = blockIdx.y * 128, n0 = blockIdx.x * 128;
  int wm = wave >> 1, wn = wave & 1;
  int srow = t >> 2, scol = (t & 3) * 8;
  const u16* Abase = A + (size_t)(m0 + srow) * 1024 + scol;
  const u16* Bbase = Bt + (size_t)(n0 + srow) * 1024 + scol;
  u16* la = lds_a + wave * 512;  // wave-uniform LDS base; HW adds lane*16B
  u16* lb = lds_b + wave * 512;
  f32x4 acc[4][4] = {};
  for (int kt = 0; kt < 32; ++kt) {
    int k0 = kt * 32;
#pragma unroll
    for (int r = 0; r < 2; ++r) {
      __builtin_amdgcn_global_load_lds(
          (const __attribute__((address_space(1))) u32*)(Abase + (size_t)r * 64 * 1024 + k0),
          (__attribute__((address_space(3))) u32*)(la + r * 2048), 16, 0, 0);
      __builtin_amdgcn_global_load_lds(
          (const __attribute__((address_space(1))) u32*)(Bbase + (size_t)r * 64 * 1024 + k0),
          (__attribute__((address_space(3))) u32*)(lb + r * 2048), 16, 0, 0);
    }
    __syncthreads();
    bfrag af[4], bf[4];
#pragma unroll
    for (int mi = 0; mi < 4; ++mi)
      af[mi] = *reinterpret_cast<const bfrag*>(&lds_a[(wm * 64 + mi * 16 + col) * 32 + 8 * g]);
#pragma unroll
    for (int ni = 0; ni < 4; ++ni)
      bf[ni] = *reinterpret_cast<const bfrag*>(&lds_b[(wn * 64 + ni * 16 + col) * 32 + 8 * g]);
#pragma unroll
    for (int mi = 0; mi < 4; ++mi)
#pragma unroll
      for (int ni = 0; ni < 4; ++ni)
        acc[mi][ni] = __builtin_amdgcn_mfma_f32_16x16x32_bf16(af[mi], bf[ni], acc[mi][ni], 0, 0, 0);
    __syncthreads();
  }
#pragma unroll
  for (int mi = 0; mi < 4; ++mi)
#pragma unroll
    for (int ni = 0; ni < 4; ++ni) {
      int row = m0 + wm * 64 + mi * 16 + g * 4;
      int cc = n0 + wn * 64 + ni * 16 + col;
#pragma unroll
      for (int r = 0; r < 4; ++r)
        C[(size_t)(row + r) * N + cc] = acc[mi][ni][r];
    }
}

// ---------------- kernel 5: RoPE + scatter QKV(f32, ROWSx1536) -> Qr/Kr/Vt bf16 ----------------
__global__ void rope_scatter_k(const float* __restrict__ QKV, const float* __restrict__ cosT,
                               const float* __restrict__ sinT, u16* __restrict__ Qr,
                               u16* __restrict__ Kr, u16* __restrict__ Vt) {
  int idx = blockIdx.x * blockDim.x + threadIdx.x;  // ROWS*768 exactly
  int row = idx / 768, u = idx - row * 768;
  int b = row >> 11, s = row & 2047;
  const float* qkv = QKV + (size_t)row * 1536;
  if (u < 640) {  // Q pairs (u<512) and K pairs
    int i;
    float x1, x2;
    u16* dst;
    size_t dsto;
    if (u < 512) {
      int hq = u >> 5; i = u & 31;
      x1 = qkv[2 * u]; x2 = qkv[2 * u + 1];
      dst = Qr; dsto = ((size_t)(b * NHQ + hq) * S_LEN + s) * HD + 2 * i;
    } else {
      int v = u - 512; int kh = v >> 5; i = v & 31;
      x1 = qkv[1024 + 2 * v]; x2 = qkv[1024 + 2 * v + 1];
      dst = Kr; dsto = ((size_t)(b * NHKV + kh) * S_LEN + s) * HD + 2 * i;
    }
    float cs = cosT[s * 32 + i], sn = sinT[s * 32 + i];
    float o1 = x1 * cs - x2 * sn;
    float o2 = x1 * sn + x2 * cs;
    u32 pk = (u32)f2b(o1) | ((u32)f2b(o2) << 16);
    *reinterpret_cast<u32*>(dst + dsto) = pk;
  } else {  // V: transpose into (b,kv,64,S)
    int j = u - 640; int kh = j >> 5; int d = 2 * (j & 31);
    float v1 = qkv[1280 + 2 * j], v2 = qkv[1280 + 2 * j + 1];
    size_t base = ((size_t)(b * NHKV + kh) * HD + d) * S_LEN + s;
    Vt[base] = f2b(v1);
    Vt[base + S_LEN] = f2b(v2);
  }
}

// ---------------- kernel 6: sliding-window flash attention ----------------
// grid: b*NHQ*32 blocks; 4 waves/block, each wave owns 16 q-rows independently.
__global__ __launch_bounds__(256) void attn_k(const u16* __restrict__ Qr, const u16* __restrict__ Kr,
                                              const u16* __restrict__ Vt, u16* __restrict__ ctx) {
  __shared__ u16 plds[4][16 * 32];
  int bid = blockIdx.x;
  int qb = bid & 31, h = (bid >> 5) & 15, b = bid >> 9;
  int wave = threadIdx.x >> 6, lane = threadIdx.x & 63;
  int g = lane >> 4, col = lane & 15;
  int kv = h >> 2;
  int qw0 = qb * 64 + wave * 16;
  const u16* Qb = Qr + (size_t)(b * NHQ + h) * S_LEN * HD;
  const u16* Kb = Kr + (size_t)(b * NHKV + kv) * S_LEN * HD;
  const u16* Vb = Vt + (size_t)(b * NHKV + kv) * HD * S_LEN;
  bfrag qf0 = *reinterpret_cast<const bfrag*>(&Qb[(size_t)(qw0 + col) * HD + 8 * g]);
  bfrag qf1 = *reinterpret_cast<const bfrag*>(&Qb[(size_t)(qw0 + col) * HD + 32 + 8 * g]);
  f32x4 octx[4] = {};
  float mrow[4] = {-1e30f, -1e30f, -1e30f, -1e30f};
  float lrow[4] = {0.f, 0.f, 0.f, 0.f};
  int qi[4];
#pragma unroll
  for (int r = 0; r < 4; ++r) qi[r] = qw0 + g * 4 + r;
  int lo = qw0 - HALFW; if (lo < 0) lo = 0; lo &= ~31;
  int hi = qw0 + 16 + HALFW; if (hi > S_LEN) hi = S_LEN;
  u16* pbuf = &plds[wave][0];
  for (int c0 = lo; c0 < hi; c0 += 32) {
    f32x4 sc[2];
#pragma unroll
    for (int kt = 0; kt < 2; ++kt) {
      int key = c0 + kt * 16 + col;
      int ka = key < S_LEN ? key : S_LEN - 1;  // address clamp; mask handles value
      f32x4 a = {};
      bfrag kf0 = *reinterpret_cast<const bfrag*>(&Kb[(size_t)ka * HD + 8 * g]);
      a = __builtin_amdgcn_mfma_f32_16x16x32_bf16(qf0, kf0, a, 0, 0, 0);
      bfrag kf1 = *reinterpret_cast<const bfrag*>(&Kb[(size_t)ka * HD + 32 + 8 * g]);
      a = __builtin_amdgcn_mfma_f32_16x16x32_bf16(qf1, kf1, a, 0, 0, 0);
      sc[kt] = a;
    }
    int kj0 = c0 + col, kj1 = c0 + 16 + col;
    float s0[4], s1[4];
    bool v0[4], v1[4];
#pragma unroll
    for (int r = 0; r < 4; ++r) {
      v0[r] = (kj0 < S_LEN) && (kj0 >= qi[r] - HALFW) && (kj0 <= qi[r] + HALFW);
      v1[r] = (kj1 < S_LEN) && (kj1 >= qi[r] - HALFW) && (kj1 <= qi[r] + HALFW);
      s0[r] = v0[r] ? sc[0][r] * 0.125f : -1e30f;
      s1[r] = v1[r] ? sc[1][r] * 0.125f : -1e30f;
    }
    float mx[4];
#pragma unroll
    for (int r = 0; r < 4; ++r) mx[r] = fmaxf(s0[r], s1[r]);
#pragma unroll
    for (int off = 1; off < 16; off <<= 1)
#pragma unroll
      for (int r = 0; r < 4; ++r) mx[r] = fmaxf(mx[r], __shfl_xor(mx[r], off));
    float alpha[4], mn[4];
#pragma unroll
    for (int r = 0; r < 4; ++r) {
      mn[r] = fmaxf(mrow[r], mx[r]);
      alpha[r] = __expf(mrow[r] - mn[r]);
      mrow[r] = mn[r];
    }
    float p0[4], p1[4];
#pragma unroll
    for (int r = 0; r < 4; ++r) {
      p0[r] = v0[r] ? __expf(s0[r] - mn[r]) : 0.f;  // explicit predicate: fully-masked tile -> p=0
      p1[r] = v1[r] ? __expf(s1[r] - mn[r]) : 0.f;
    }
    float rs[4];
#pragma unroll
    for (int r = 0; r < 4; ++r) rs[r] = p0[r] + p1[r];
#pragma unroll
    for (int off = 1; off < 16; off <<= 1)
#pragma unroll
      for (int r = 0; r < 4; ++r) rs[r] += __shfl_xor(rs[r], off);
#pragma unroll
    for (int r = 0; r < 4; ++r) lrow[r] = lrow[r] * alpha[r] + rs[r];
#pragma unroll
    for (int n = 0; n < 4; ++n)
#pragma unroll
      for (int r = 0; r < 4; ++r) octx[n][r] *= alpha[r];
    // P -> LDS (score layout) -> A-fragment layout
#pragma unroll
    for (int r = 0; r < 4; ++r) {
      pbuf[(g * 4 + r) * 32 + col] = f2b(p0[r]);
      pbuf[(g * 4 + r) * 32 + 16 + col] = f2b(p1[r]);
    }
    asm volatile("s_waitcnt lgkmcnt(0)" ::: "memory");
    bfrag pa = *reinterpret_cast<const bfrag*>(&pbuf[col * 32 + 8 * g]);
    asm volatile("" ::: "memory");
    int kb = c0 + 8 * g;
    if (kb > S_LEN - 8) kb = S_LEN - 8;  // address clamp; p=0 kills masked keys
#pragma unroll
    for (int n = 0; n < 4; ++n) {
      bfrag vf = *reinterpret_cast<const bfrag*>(&Vb[(size_t)(n * 16 + col) * S_LEN + kb]);
      octx[n] = __builtin_amdgcn_mfma_f32_16x16x32_bf16(pa, vf, octx[n], 0, 0, 0);
    }
  }
  u16* cb = ctx + (size_t)b * S_LEN * DMODEL + h * HD;
#pragma unroll
  for (int n = 0; n < 4; ++n)
#pragma unroll
    for (int r = 0; r < 4; ++r) {
      float v = octx[n][r] / lrow[r];
      cb[(size_t)(qw0 + g * 4 + r) * DMODEL + n * 16 + col] = f2b(v);
    }
}

extern "C" void kernel_launch(void* const* d_in, const int* in_sizes, int n_in,
                              void* d_out, int out_size, void* d_ws, size_t ws_size,
                              hipStream_t stream) {
  (void)in_sizes; (void)n_in; (void)out_size; (void)ws_size;
  const float* x  = (const float*)d_in[0];
  const float* Wq = (const float*)d_in[1];
  const float* Wk = (const float*)d_in[2];
  const float* Wv = (const float*)d_in[3];
  const float* Wo = (const float*)d_in[4];
  char* ws = (char*)d_ws;
  u16*   xb     = (u16*)(ws + 0);          //  8,388,608
  u16*   Wcat_t = (u16*)(ws + 8388608);    //  3,145,728  (1536 x 1024)
  u16*   Wo_t   = (u16*)(ws + 11534336);   //  2,097,152
  float* QKV    = (float*)(ws + 13631488); // 25,165,824  (4096 x 1536 f32)
  u16*   Qr     = (u16*)(ws + 38797312);   //  8,388,608  (b,h,s,64)
  u16*   Kr     = (u16*)(ws + 47185920);   //  2,097,152  (b,kv,s,64)
  u16*   Vt     = (u16*)(ws + 49283072);   //  2,097,152  (b,kv,64,s)
  u16*   ctxb   = (u16*)(ws + 51380224);   //  8,388,608
  float* cosT   = (float*)(ws + 59768832); //    262,144
  float* sinT   = (float*)(ws + 60030976); //    262,144  -> total 60,293,120 B

  rope_table_k<<<256, 256, 0, stream>>>(cosT, sinT);
  cast_x_k<<<4096, 256, 0, stream>>>(x, xb);
  dim3 tb(32, 8);
  transpose_cast_k<<<dim3(32, 32), tb, 0, stream>>>(Wq, 1024, Wcat_t);
  transpose_cast_k<<<dim3(32, 8),  tb, 0, stream>>>(Wk, 256,  Wcat_t + (size_t)1024 * 1024);
  transpose_cast_k<<<dim3(32, 8),  tb, 0, stream>>>(Wv, 256,  Wcat_t + (size_t)1280 * 1024);
  transpose_cast_k<<<dim3(32, 32), tb, 0, stream>>>(Wo, 1024, Wo_t);
  gemm_bt_k<<<dim3(12, 32), 256, 0, stream>>>(xb, Wcat_t, QKV, 1536);
  rope_scatter_k<<<12288, 256, 0, stream>>>(QKV, cosT, sinT, Qr, Kr, Vt);
  attn_k<<<1024, 256, 0, stream>>>(Qr, Kr, Vt, ctxb);
  gemm_bt_k<<<dim3(8, 32), 256, 0, stream>>>(ctxb, Wo_t, (float*)d_out, 1024);
}

// Round 2
// 127.241 us; speedup vs baseline: 1.0046x; 1.0046x over previous
//
#include <hip/hip_runtime.h>

typedef unsigned short u16;
typedef unsigned int u32;
typedef __attribute__((ext_vector_type(8))) short bfrag;   // 8 x bf16 (4 VGPRs)
typedef __attribute__((ext_vector_type(4))) float f32x4;

#define S_LEN 2048
#define DMODEL 1024
#define NHQ 16
#define NHKV 4
#define HD 64
#define HALFW 128
#define ROWS 4096   // B*S

__device__ __forceinline__ u16 f2b(float f) {
  u32 x = __float_as_uint(f);
  return (u16)((x + 0x7fffu + ((x >> 16) & 1u)) >> 16);  // RNE
}

__device__ __forceinline__ u32 cvtpk(float lo, float hi) {
  u32 r;
  asm("v_cvt_pk_bf16_f32 %0, %1, %2" : "=v"(r) : "v"(lo), "v"(hi));
  return r;
}

__device__ __forceinline__ float fexp(float x) {  // 2^x
  float r;
  asm("v_exp_f32 %0, %1" : "=v"(r) : "v"(x));
  return r;
}

// ---------------- kernel 1: RoPE table (double precision trig) ----------------
__global__ void rope_table_k(float* __restrict__ cosT, float* __restrict__ sinT) {
  int idx = blockIdx.x * blockDim.x + threadIdx.x;  // S_LEN*32 exactly
  int s = idx >> 5, i = idx & 31;
  double inv = pow(10000.0, -(double)(2 * i) / 64.0);
  double ang = (double)s * inv;
  cosT[idx] = (float)cos(ang);
  sinT[idx] = (float)sin(ang);
}

// ---------------- kernel 2: cast x -> bf16 ----------------
__global__ void cast_x_k(const float* __restrict__ x, u16* __restrict__ xb) {
  int i = (blockIdx.x * blockDim.x + threadIdx.x) * 4;
  float4 v = *reinterpret_cast<const float4*>(x + i);
  uint2 p;
  p.x = (u32)f2b(v.x) | ((u32)f2b(v.y) << 16);
  p.y = (u32)f2b(v.z) | ((u32)f2b(v.w) << 16);
  *reinterpret_cast<uint2*>(xb + i) = p;
}

// ---------------- kernel 3: transpose-cast weight (K=1024 rows x ncols) -> (ncols x 1024) bf16
__global__ void transpose_cast_k(const float* __restrict__ src, int ncols, u16* __restrict__ dst) {
  __shared__ float tile[32][33];
  int k0 = blockIdx.x * 32, n0 = blockIdx.y * 32;
  int tx = threadIdx.x, ty = threadIdx.y;  // 32 x 8
#pragma unroll
  for (int j = 0; j < 4; ++j)
    tile[ty + 8 * j][tx] = src[(size_t)(k0 + ty + 8 * j) * ncols + n0 + tx];
  __syncthreads();
#pragma unroll
  for (int j = 0; j < 4; ++j)
    dst[(size_t)(n0 + ty + 8 * j) * 1024 + k0 + tx] = f2b(tile[tx][ty + 8 * j]);
}

// ---------------- kernel 4/7: 128x128 bf16 GEMM, C fp32. A:(M,1024) row, Bt:(N,1024) row ----------------
__global__ __launch_bounds__(256) void gemm_bt_k(const u16* __restrict__ A, const u16* __restrict__ Bt,
                                                 float* __restrict__ C, int N) {
  __shared__ u16 lds_a[128 * 32];
  __shared__ u16 lds_b[128 * 32];
  int t = threadIdx.x;
  int wave = t >> 6, lane = t & 63;
  int g = lane >> 4, col = lane & 15;
  int m0 = blockIdx.y * 128, n0 = blockIdx.x * 128;
  int wm = wave >> 1, wn = wave & 1;
  int srow = t >> 2, scol = (t & 3) * 8;
  const u16* Abase = A + (size_t)(m0 + srow) * 1024 + scol;
  const u16* Bbase = Bt + (size_t)(n0 + srow) * 1024 + scol;
  u16* la = lds_a + wave * 512;  // wave-uniform LDS base; HW adds lane*16B
  u16* lb = lds_b + wave * 512;
  f32x4 acc[4][4] = {};
  for (int kt = 0; kt < 32; ++kt) {
    int k0 = kt * 32;
#pragma unroll
    for (int r = 0; r < 2; ++r) {
      __builtin_amdgcn_global_load_lds(
          (const __attribute__((address_space(1))) u32*)(Abase + (size_t)r * 64 * 1024 + k0),
          (__attribute__((address_space(3))) u32*)(la + r * 2048), 16, 0, 0);
      __builtin_amdgcn_global_load_lds(
          (const __attribute__((address_space(1))) u32*)(Bbase + (size_t)r * 64 * 1024 + k0),
          (__attribute__((address_space(3))) u32*)(lb + r * 2048), 16, 0, 0);
    }
    __syncthreads();
    bfrag af[4], bf[4];
#pragma unroll
    for (int mi = 0; mi < 4; ++mi)
      af[mi] = *reinterpret_cast<const bfrag*>(&lds_a[(wm * 64 + mi * 16 + col) * 32 + 8 * g]);
#pragma unroll
    for (int ni = 0; ni < 4; ++ni)
      bf[ni] = *reinterpret_cast<const bfrag*>(&lds_b[(wn * 64 + ni * 16 + col) * 32 + 8 * g]);
#pragma unroll
    for (int mi = 0; mi < 4; ++mi)
#pragma unroll
      for (int ni = 0; ni < 4; ++ni)
        acc[mi][ni] = __builtin_amdgcn_mfma_f32_16x16x32_bf16(af[mi], bf[ni], acc[mi][ni], 0, 0, 0);
    __syncthreads();
  }
#pragma unroll
  for (int mi = 0; mi < 4; ++mi)
#pragma unroll
    for (int ni = 0; ni < 4; ++ni) {
      int row = m0 + wm * 64 + mi * 16 + g * 4;
      int cc = n0 + wn * 64 + ni * 16 + col;
#pragma unroll
      for (int r = 0; r < 4; ++r)
        C[(size_t)(row + r) * N + cc] = acc[mi][ni][r];
    }
}

// ---------------- kernel 5: RoPE + scatter QKV(f32, ROWSx1536) -> Qr/Kr/Vt bf16 ----------------
// Q additionally pre-scaled by 0.125*log2(e) so attention can use v_exp_f32 directly on raw QK dots.
#define QSCALE 0.1803368801111244f
__global__ void rope_scatter_k(const float* __restrict__ QKV, const float* __restrict__ cosT,
                               const float* __restrict__ sinT, u16* __restrict__ Qr,
                               u16* __restrict__ Kr, u16* __restrict__ Vt) {
  int idx = blockIdx.x * blockDim.x + threadIdx.x;  // ROWS*768 exactly
  int row = idx / 768, u = idx - row * 768;
  int b = row >> 11, s = row & 2047;
  const float* qkv = QKV + (size_t)row * 1536;
  if (u < 640) {  // Q pairs (u<512) and K pairs
    int i;
    float x1, x2;
    u16* dst;
    size_t dsto;
    bool isq = u < 512;
    if (isq) {
      int hq = u >> 5; i = u & 31;
      x1 = qkv[2 * u]; x2 = qkv[2 * u + 1];
      dst = Qr; dsto = ((size_t)(b * NHQ + hq) * S_LEN + s) * HD + 2 * i;
    } else {
      int v = u - 512; int kh = v >> 5; i = v & 31;
      x1 = qkv[1024 + 2 * v]; x2 = qkv[1024 + 2 * v + 1];
      dst = Kr; dsto = ((size_t)(b * NHKV + kh) * S_LEN + s) * HD + 2 * i;
    }
    float cs = cosT[s * 32 + i], sn = sinT[s * 32 + i];
    float o1 = x1 * cs - x2 * sn;
    float o2 = x1 * sn + x2 * cs;
    if (isq) { o1 *= QSCALE; o2 *= QSCALE; }
    u32 pk = (u32)f2b(o1) | ((u32)f2b(o2) << 16);
    *reinterpret_cast<u32*>(dst + dsto) = pk;
  } else {  // V: transpose into (b,kv,64,S)
    int j = u - 640; int kh = j >> 5; int d = 2 * (j & 31);
    float v1 = qkv[1280 + 2 * j], v2 = qkv[1280 + 2 * j + 1];
    size_t base = ((size_t)(b * NHKV + kh) * HD + d) * S_LEN + s;
    Vt[base] = f2b(v1);
    Vt[base + S_LEN] = f2b(v2);
  }
}

// ---------------- kernel 6: sliding-window flash attention (swapped-operand, no LDS) ----------------
// grid: b*NHQ*32 blocks; 4 waves/block, each wave owns 16 q-rows independently.
// S^T = mfma(K,Q): lane(g,col) holds S[key=c0+16kt+4g+r][q=q0+col].
// p = v_exp_f32(raw dot) -- 0.125*log2e pre-folded into Q; fixed-max shift cancels in p*v/sum(p).
// P B-frag built in-register via cvt_pk + 8x ds_bpermute; O^T = mfma(V,P) -> q is column index.
__global__ __launch_bounds__(256) void attn_k(const u16* __restrict__ Qr, const u16* __restrict__ Kr,
                                              const u16* __restrict__ Vt, u16* __restrict__ ctx) {
  int bid = blockIdx.x;
  int qb = bid & 31, h = (bid >> 5) & 15, b = bid >> 9;
  int wave = threadIdx.x >> 6, lane = threadIdx.x & 63;
  int g = lane >> 4, col = lane & 15;
  int kv = h >> 2;
  int q0 = qb * 64 + wave * 16;
  const u16* Qb = Qr + (size_t)(b * NHQ + h) * S_LEN * HD;
  const u16* Kb = Kr + (size_t)(b * NHKV + kv) * S_LEN * HD;
  const u16* Vb = Vt + (size_t)(b * NHKV + kv) * HD * S_LEN;
  // Q as B-frag (n=q): lane(g,col) -> q=q0+col, d=8g..8g+7
  bfrag qf0 = *reinterpret_cast<const bfrag*>(&Qb[(size_t)(q0 + col) * HD + 8 * g]);
  bfrag qf1 = *reinterpret_cast<const bfrag*>(&Qb[(size_t)(q0 + col) * HD + 32 + 8 * g]);
  f32x4 octx[4] = {};
  float lacc = 0.f;
  int qi = q0 + col;
  bool hi5 = (threadIdx.x & 32) != 0;                    // target g>>1 (kt select)
  int l0b = (col + ((lane >> 4) & 1) * 32) << 2;         // src lane for frag words 0,1 (bytes)
  int l1b = l0b + 64;                                    // src lane for frag words 2,3
  int lo = q0 - HALFW; if (lo < 0) lo = 0; lo &= ~31;
  int hi = q0 + 16 + HALFW; if (hi > S_LEN) hi = S_LEN;
  for (int c0 = lo; c0 < hi; c0 += 32) {
    f32x4 s0 = {}, s1 = {};
    __builtin_amdgcn_s_setprio(1);
    {
      bfrag kf = *reinterpret_cast<const bfrag*>(&Kb[(size_t)(c0 + col) * HD + 8 * g]);
      s0 = __builtin_amdgcn_mfma_f32_16x16x32_bf16(kf, qf0, s0, 0, 0, 0);
      kf = *reinterpret_cast<const bfrag*>(&Kb[(size_t)(c0 + col) * HD + 32 + 8 * g]);
      s0 = __builtin_amdgcn_mfma_f32_16x16x32_bf16(kf, qf1, s0, 0, 0, 0);
      kf = *reinterpret_cast<const bfrag*>(&Kb[(size_t)(c0 + 16 + col) * HD + 8 * g]);
      s1 = __builtin_amdgcn_mfma_f32_16x16x32_bf16(kf, qf0, s1, 0, 0, 0);
      kf = *reinterpret_cast<const bfrag*>(&Kb[(size_t)(c0 + 16 + col) * HD + 32 + 8 * g]);
      s1 = __builtin_amdgcn_mfma_f32_16x16x32_bf16(kf, qf1, s1, 0, 0, 0);
    }
    __builtin_amdgcn_s_setprio(0);
    float p0[4], p1[4];
    bool full = (c0 >= q0 + 15 - HALFW) && (c0 + 31 <= q0 + HALFW);
    if (full) {
#pragma unroll
      for (int r = 0; r < 4; ++r) { p0[r] = fexp(s0[r]); p1[r] = fexp(s1[r]); }
    } else {
      int d0 = c0 + 4 * g - qi + HALFW;  // key - qi + 128 for kt=0,r=0
#pragma unroll
      for (int r = 0; r < 4; ++r) {
        p0[r] = ((u32)(d0 + r) <= 2u * HALFW) ? fexp(s0[r]) : 0.f;
        p1[r] = ((u32)(d0 + 16 + r) <= 2u * HALFW) ? fexp(s1[r]) : 0.f;
      }
    }
    lacc += ((p0[0] + p0[1]) + (p0[2] + p0[3])) + ((p1[0] + p1[1]) + (p1[2] + p1[3]));
    // pack: word (2*kt + rpair), low half = even r
    u32 pk0 = cvtpk(p0[0], p0[1]), pk1 = cvtpk(p0[2], p0[3]);
    u32 pk2 = cvtpk(p1[0], p1[1]), pk3 = cvtpk(p1[2], p1[3]);
    // redistribute to B-frag: target lane(g~,q): words w=0,1 from lane l0, w=2,3 from lane l1;
    // word source register = pk[2*(g~>>1) + (w&1)] -> bpermute both kt options, select by hi5.
    u32 a0 = (u32)__builtin_amdgcn_ds_bpermute(l0b, (int)pk0);
    u32 b0 = (u32)__builtin_amdgcn_ds_bpermute(l0b, (int)pk2);
    u32 a1 = (u32)__builtin_amdgcn_ds_bpermute(l0b, (int)pk1);
    u32 b1 = (u32)__builtin_amdgcn_ds_bpermute(l0b, (int)pk3);
    u32 a2 = (u32)__builtin_amdgcn_ds_bpermute(l1b, (int)pk0);
    u32 b2 = (u32)__builtin_amdgcn_ds_bpermute(l1b, (int)pk2);
    u32 a3 = (u32)__builtin_amdgcn_ds_bpermute(l1b, (int)pk1);
    u32 b3 = (u32)__builtin_amdgcn_ds_bpermute(l1b, (int)pk3);
    union { bfrag f; u32 w[4]; } pb;
    pb.w[0] = hi5 ? b0 : a0;
    pb.w[1] = hi5 ? b1 : a1;
    pb.w[2] = hi5 ? b2 : a2;
    pb.w[3] = hi5 ? b3 : a3;
    __builtin_amdgcn_s_setprio(1);
#pragma unroll
    for (int n = 0; n < 4; ++n) {
      bfrag vf = *reinterpret_cast<const bfrag*>(&Vb[(size_t)(n * 16 + col) * S_LEN + c0 + 8 * g]);
      octx[n] = __builtin_amdgcn_mfma_f32_16x16x32_bf16(vf, pb.f, octx[n], 0, 0, 0);
    }
    __builtin_amdgcn_s_setprio(0);
  }
  float l = lacc + __shfl_xor(lacc, 16);
  l += __shfl_xor(l, 32);
  float linv = __builtin_amdgcn_rcpf(l);
  // lane(g,col): q=q0+col, d = n*16+4g+r
  u16* cb = ctx + (size_t)b * S_LEN * DMODEL + (size_t)(q0 + col) * DMODEL + h * HD;
#pragma unroll
  for (int n = 0; n < 4; ++n) {
    uint2 o;
    o.x = cvtpk(octx[n][0] * linv, octx[n][1] * linv);
    o.y = cvtpk(octx[n][2] * linv, octx[n][3] * linv);
    *reinterpret_cast<uint2*>(cb + n * 16 + 4 * g) = o;
  }
}

extern "C" void kernel_launch(void* const* d_in, const int* in_sizes, int n_in,
                              void* d_out, int out_size, void* d_ws, size_t ws_size,
                              hipStream_t stream) {
  (void)in_sizes; (void)n_in; (void)out_size; (void)ws_size;
  const float* x  = (const float*)d_in[0];
  const float* Wq = (const float*)d_in[1];
  const float* Wk = (const float*)d_in[2];
  const float* Wv = (const float*)d_in[3];
  const float* Wo = (const float*)d_in[4];
  char* ws = (char*)d_ws;
  u16*   xb     = (u16*)(ws + 0);          //  8,388,608
  u16*   Wcat_t = (u16*)(ws + 8388608);    //  3,145,728  (1536 x 1024)
  u16*   Wo_t   = (u16*)(ws + 11534336);   //  2,097,152
  float* QKV    = (float*)(ws + 13631488); // 25,165,824  (4096 x 1536 f32)
  u16*   Qr     = (u16*)(ws + 38797312);   //  8,388,608  (b,h,s,64)
  u16*   Kr     = (u16*)(ws + 47185920);   //  2,097,152  (b,kv,s,64)
  u16*   Vt     = (u16*)(ws + 49283072);   //  2,097,152  (b,kv,64,s)
  u16*   ctxb   = (u16*)(ws + 51380224);   //  8,388,608
  float* cosT   = (float*)(ws + 59768832); //    262,144
  float* sinT   = (float*)(ws + 60030976); //    262,144  -> total 60,293,120 B

  rope_table_k<<<256, 256, 0, stream>>>(cosT, sinT);
  cast_x_k<<<4096, 256, 0, stream>>>(x, xb);
  dim3 tb(32, 8);
  transpose_cast_k<<<dim3(32, 32), tb, 0, stream>>>(Wq, 1024, Wcat_t);
  transpose_cast_k<<<dim3(32, 8),  tb, 0, stream>>>(Wk, 256,  Wcat_t + (size_t)1024 * 1024);
  transpose_cast_k<<<dim3(32, 8),  tb, 0, stream>>>(Wv, 256,  Wcat_t + (size_t)1280 * 1024);
  transpose_cast_k<<<dim3(32, 32), tb, 0, stream>>>(Wo, 1024, Wo_t);
  gemm_bt_k<<<dim3(12, 32), 256, 0, stream>>>(xb, Wcat_t, QKV, 1536);
  rope_scatter_k<<<12288, 256, 0, stream>>>(QKV, cosT, sinT, Qr, Kr, Vt);
  attn_k<<<1024, 256, 0, stream>>>(Qr, Kr, Vt, ctxb);
  gemm_bt_k<<<dim3(8, 32), 256, 0, stream>>>(ctxb, Wo_t, (float*)d_out, 1024);
}

// Round 3
// 109.823 us; speedup vs baseline: 1.1639x; 1.1586x over previous
//
#include <hip/hip_runtime.h>

typedef unsigned short u16;
typedef unsigned int u32;
typedef __attribute__((ext_vector_type(8))) short bfrag;   // 8 x bf16 (4 VGPRs)
typedef __attribute__((ext_vector_type(4))) float f32x4;

#define S_LEN 2048
#define DMODEL 1024
#define NHQ 16
#define NHKV 4
#define HD 64
#define HALFW 128
#define ROWS 4096   // B*S
#define QSCALE 0.1803368801111244f   // 0.125 * log2(e)

__device__ __forceinline__ u16 f2b(float f) {
  u32 x = __float_as_uint(f);
  return (u16)((x + 0x7fffu + ((x >> 16) & 1u)) >> 16);  // RNE
}

__device__ __forceinline__ u32 cvtpk(float lo, float hi) {
  u32 r;
  asm("v_cvt_pk_bf16_f32 %0, %1, %2" : "=v"(r) : "v"(lo), "v"(hi));
  return r;
}

__device__ __forceinline__ float fexp(float x) {  // 2^x
  float r;
  asm("v_exp_f32 %0, %1" : "=v"(r) : "v"(x));
  return r;
}

// ---------------- kernel 1: RoPE table (double precision trig), packed {cos,sin} ----------------
__global__ void rope_table_k(float2* __restrict__ csT) {
  int idx = blockIdx.x * blockDim.x + threadIdx.x;  // S_LEN*32 exactly
  int s = idx >> 5, i = idx & 31;
  double inv = pow(10000.0, -(double)(2 * i) / 64.0);
  double ang = (double)s * inv;
  csT[idx] = make_float2((float)cos(ang), (float)sin(ang));
}

// ---------------- kernel 2: cast x -> bf16 ----------------
__global__ void cast_x_k(const float* __restrict__ x, u16* __restrict__ xb) {
  int i = (blockIdx.x * blockDim.x + threadIdx.x) * 4;
  float4 v = *reinterpret_cast<const float4*>(x + i);
  uint2 p;
  p.x = (u32)f2b(v.x) | ((u32)f2b(v.y) << 16);
  p.y = (u32)f2b(v.z) | ((u32)f2b(v.w) << 16);
  *reinterpret_cast<uint2*>(xb + i) = p;
}

// ---------------- kernel 3: transpose-cast ALL weights in one launch ----------------
// grid.y: 0..31 Wq -> Wcat_t rows 0..1023; 32..39 Wk -> rows 1024..1279;
//         40..47 Wv -> rows 1280..1535; 48..79 Wo -> Wo_t rows 0..1023.
__global__ void transpose_cast_all_k(const float* __restrict__ Wq, const float* __restrict__ Wk,
                                     const float* __restrict__ Wv, const float* __restrict__ Wo,
                                     u16* __restrict__ Wcat_t, u16* __restrict__ Wo_t) {
  __shared__ float tile[32][33];
  int k0 = blockIdx.x * 32;
  int y = blockIdx.y;
  const float* src; u16* dst; int ncols, n0;
  if (y < 32)      { src = Wq; dst = Wcat_t;                       ncols = 1024; n0 = y * 32; }
  else if (y < 40) { src = Wk; dst = Wcat_t + (size_t)1024 * 1024; ncols = 256;  n0 = (y - 32) * 32; }
  else if (y < 48) { src = Wv; dst = Wcat_t + (size_t)1280 * 1024; ncols = 256;  n0 = (y - 40) * 32; }
  else             { src = Wo; dst = Wo_t;                         ncols = 1024; n0 = (y - 48) * 32; }
  int tx = threadIdx.x, ty = threadIdx.y;  // 32 x 8
#pragma unroll
  for (int j = 0; j < 4; ++j)
    tile[ty + 8 * j][tx] = src[(size_t)(k0 + ty + 8 * j) * ncols + n0 + tx];
  __syncthreads();
#pragma unroll
  for (int j = 0; j < 4; ++j)
    dst[(size_t)(n0 + ty + 8 * j) * 1024 + k0 + tx] = f2b(tile[tx][ty + 8 * j]);
}

// ---------------- kernel 4: QKV GEMM with fused RoPE/scale/scatter epilogue ----------------
// A: xb (4096 x 1024 bf16), Bt: Wcat_t (1536 x 1024 bf16).
// Epilogue: n<1024 -> Q (RoPE + QSCALE -> Qr), 1024..1279 -> K (RoPE -> Kr), >=1280 -> V (-> Vt transposed).
__global__ __launch_bounds__(256) void gemm_qkv_k(const u16* __restrict__ A, const u16* __restrict__ Bt,
                                                  const float2* __restrict__ csT,
                                                  u16* __restrict__ Qr, u16* __restrict__ Kr,
                                                  u16* __restrict__ Vt) {
  __shared__ u16 lds_a[128 * 32];
  __shared__ u16 lds_b[128 * 32];
  int t = threadIdx.x;
  int wave = t >> 6, lane = t & 63;
  int g = lane >> 4, col = lane & 15;
  int m0 = blockIdx.y * 128, n0 = blockIdx.x * 128;
  int wm = wave >> 1, wn = wave & 1;
  int srow = t >> 2, scol = (t & 3) * 8;
  const u16* Abase = A + (size_t)(m0 + srow) * 1024 + scol;
  const u16* Bbase = Bt + (size_t)(n0 + srow) * 1024 + scol;
  u16* la = lds_a + wave * 512;
  u16* lb = lds_b + wave * 512;
  f32x4 acc[4][4] = {};
  for (int kt = 0; kt < 32; ++kt) {
    int k0 = kt * 32;
#pragma unroll
    for (int r = 0; r < 2; ++r) {
      __builtin_amdgcn_global_load_lds(
          (const __attribute__((address_space(1))) u32*)(Abase + (size_t)r * 64 * 1024 + k0),
          (__attribute__((address_space(3))) u32*)(la + r * 2048), 16, 0, 0);
      __builtin_amdgcn_global_load_lds(
          (const __attribute__((address_space(1))) u32*)(Bbase + (size_t)r * 64 * 1024 + k0),
          (__attribute__((address_space(3))) u32*)(lb + r * 2048), 16, 0, 0);
    }
    __syncthreads();
    bfrag af[4], bf[4];
#pragma unroll
    for (int mi = 0; mi < 4; ++mi)
      af[mi] = *reinterpret_cast<const bfrag*>(&lds_a[(wm * 64 + mi * 16 + col) * 32 + 8 * g]);
#pragma unroll
    for (int ni = 0; ni < 4; ++ni)
      bf[ni] = *reinterpret_cast<const bfrag*>(&lds_b[(wn * 64 + ni * 16 + col) * 32 + 8 * g]);
#pragma unroll
    for (int mi = 0; mi < 4; ++mi)
#pragma unroll
      for (int ni = 0; ni < 4; ++ni)
        acc[mi][ni] = __builtin_amdgcn_mfma_f32_16x16x32_bf16(af[mi], bf[ni], acc[mi][ni], 0, 0, 0);
    __syncthreads();
  }
  bool odd = (col & 1) != 0;
#pragma unroll
  for (int mi = 0; mi < 4; ++mi)
#pragma unroll
    for (int ni = 0; ni < 4; ++ni) {
      int cg = n0 + wn * 64 + ni * 16 + col;
      int rowbase = m0 + wm * 64 + mi * 16 + g * 4;
      if (cg < 1024) {  // ---- Q: RoPE + QSCALE ----
        int hq = cg >> 6, d = cg & 63, i = d >> 1;
        u16* dst = Qr + ((size_t)((rowbase >> 11) * NHQ + hq) * S_LEN + (rowbase & 2047)) * HD + d;
#pragma unroll
        for (int r = 0; r < 4; ++r) {
          int s = (rowbase + r) & 2047;
          float v = acc[mi][ni][r];
          float pv = __shfl_xor(v, 1);
          float2 cs = csT[s * 32 + i];
          float o = odd ? (pv * cs.y + v * cs.x) : (v * cs.x - pv * cs.y);
          dst[(size_t)r * HD] = f2b(o * QSCALE);
        }
      } else if (cg < 1280) {  // ---- K: RoPE ----
        int j = cg - 1024;
        int kh = j >> 6, d = j & 63, i = d >> 1;
        u16* dst = Kr + ((size_t)((rowbase >> 11) * NHKV + kh) * S_LEN + (rowbase & 2047)) * HD + d;
#pragma unroll
        for (int r = 0; r < 4; ++r) {
          int s = (rowbase + r) & 2047;
          float v = acc[mi][ni][r];
          float pv = __shfl_xor(v, 1);
          float2 cs = csT[s * 32 + i];
          float o = odd ? (pv * cs.y + v * cs.x) : (v * cs.x - pv * cs.y);
          dst[(size_t)r * HD] = f2b(o);
        }
      } else {  // ---- V: transpose to (b,kv,64,S); 4 consecutive s -> one 8B store ----
        int j = cg - 1280;
        int kh = j >> 6, d = j & 63;
        int b = rowbase >> 11, s0 = rowbase & 2047;
        uint2 o;
        o.x = (u32)f2b(acc[mi][ni][0]) | ((u32)f2b(acc[mi][ni][1]) << 16);
        o.y = (u32)f2b(acc[mi][ni][2]) | ((u32)f2b(acc[mi][ni][3]) << 16);
        *reinterpret_cast<uint2*>(Vt + ((size_t)(b * NHKV + kh) * HD + d) * S_LEN + s0) = o;
      }
    }
}

// ---------------- kernel 5: plain 128x128 GEMM, C fp32 (out-proj) ----------------
__global__ __launch_bounds__(256) void gemm_bt_k(const u16* __restrict__ A, const u16* __restrict__ Bt,
                                                 float* __restrict__ C, int N) {
  __shared__ u16 lds_a[128 * 32];
  __shared__ u16 lds_b[128 * 32];
  int t = threadIdx.x;
  int wave = t >> 6, lane = t & 63;
  int g = lane >> 4, col = lane & 15;
  int m0 = blockIdx.y * 128, n0 = blockIdx.x * 128;
  int wm = wave >> 1, wn = wave & 1;
  int srow = t >> 2, scol = (t & 3) * 8;
  const u16* Abase = A + (size_t)(m0 + srow) * 1024 + scol;
  const u16* Bbase = Bt + (size_t)(n0 + srow) * 1024 + scol;
  u16* la = lds_a + wave * 512;
  u16* lb = lds_b + wave * 512;
  f32x4 acc[4][4] = {};
  for (int kt = 0; kt < 32; ++kt) {
    int k0 = kt * 32;
#pragma unroll
    for (int r = 0; r < 2; ++r) {
      __builtin_amdgcn_global_load_lds(
          (const __attribute__((address_space(1))) u32*)(Abase + (size_t)r * 64 * 1024 + k0),
          (__attribute__((address_space(3))) u32*)(la + r * 2048), 16, 0, 0);
      __builtin_amdgcn_global_load_lds(
          (const __attribute__((address_space(1))) u32*)(Bbase + (size_t)r * 64 * 1024 + k0),
          (__attribute__((address_space(3))) u32*)(lb + r * 2048), 16, 0, 0);
    }
    __syncthreads();
    bfrag af[4], bf[4];
#pragma unroll
    for (int mi = 0; mi < 4; ++mi)
      af[mi] = *reinterpret_cast<const bfrag*>(&lds_a[(wm * 64 + mi * 16 + col) * 32 + 8 * g]);
#pragma unroll
    for (int ni = 0; ni < 4; ++ni)
      bf[ni] = *reinterpret_cast<const bfrag*>(&lds_b[(wn * 64 + ni * 16 + col) * 32 + 8 * g]);
#pragma unroll
    for (int mi = 0; mi < 4; ++mi)
#pragma unroll
      for (int ni = 0; ni < 4; ++ni)
        acc[mi][ni] = __builtin_amdgcn_mfma_f32_16x16x32_bf16(af[mi], bf[ni], acc[mi][ni], 0, 0, 0);
    __syncthreads();
  }
#pragma unroll
  for (int mi = 0; mi < 4; ++mi)
#pragma unroll
    for (int ni = 0; ni < 4; ++ni) {
      int row = m0 + wm * 64 + mi * 16 + g * 4;
      int cc = n0 + wn * 64 + ni * 16 + col;
#pragma unroll
      for (int r = 0; r < 4; ++r)
        C[(size_t)(row + r) * N + cc] = acc[mi][ni][r];
    }
}

// ---------------- kernel 6: sliding-window flash attention (swapped-operand, no LDS) ----------------
__global__ __launch_bounds__(256) void attn_k(const u16* __restrict__ Qr, const u16* __restrict__ Kr,
                                              const u16* __restrict__ Vt, u16* __restrict__ ctx) {
  int bid = blockIdx.x;
  int qb = bid & 31, h = (bid >> 5) & 15, b = bid >> 9;
  int wave = threadIdx.x >> 6, lane = threadIdx.x & 63;
  int g = lane >> 4, col = lane & 15;
  int kv = h >> 2;
  int q0 = qb * 64 + wave * 16;
  const u16* Qb = Qr + (size_t)(b * NHQ + h) * S_LEN * HD;
  const u16* Kb = Kr + (size_t)(b * NHKV + kv) * S_LEN * HD;
  const u16* Vb = Vt + (size_t)(b * NHKV + kv) * HD * S_LEN;
  bfrag qf0 = *reinterpret_cast<const bfrag*>(&Qb[(size_t)(q0 + col) * HD + 8 * g]);
  bfrag qf1 = *reinterpret_cast<const bfrag*>(&Qb[(size_t)(q0 + col) * HD + 32 + 8 * g]);
  f32x4 octx[4] = {};
  float lacc = 0.f;
  int qi = q0 + col;
  bool hi5 = (threadIdx.x & 32) != 0;
  int l0b = (col + ((lane >> 4) & 1) * 32) << 2;
  int l1b = l0b + 64;
  int lo = q0 - HALFW; if (lo < 0) lo = 0; lo &= ~31;
  int hi = q0 + 16 + HALFW; if (hi > S_LEN) hi = S_LEN;
  for (int c0 = lo; c0 < hi; c0 += 32) {
    f32x4 s0 = {}, s1 = {};
    __builtin_amdgcn_s_setprio(1);
    {
      bfrag kf = *reinterpret_cast<const bfrag*>(&Kb[(size_t)(c0 + col) * HD + 8 * g]);
      s0 = __builtin_amdgcn_mfma_f32_16x16x32_bf16(kf, qf0, s0, 0, 0, 0);
      kf = *reinterpret_cast<const bfrag*>(&Kb[(size_t)(c0 + col) * HD + 32 + 8 * g]);
      s0 = __builtin_amdgcn_mfma_f32_16x16x32_bf16(kf, qf1, s0, 0, 0, 0);
      kf = *reinterpret_cast<const bfrag*>(&Kb[(size_t)(c0 + 16 + col) * HD + 8 * g]);
      s1 = __builtin_amdgcn_mfma_f32_16x16x32_bf16(kf, qf0, s1, 0, 0, 0);
      kf = *reinterpret_cast<const bfrag*>(&Kb[(size_t)(c0 + 16 + col) * HD + 32 + 8 * g]);
      s1 = __builtin_amdgcn_mfma_f32_16x16x32_bf16(kf, qf1, s1, 0, 0, 0);
    }
    __builtin_amdgcn_s_setprio(0);
    float p0[4], p1[4];
    bool full = (c0 >= q0 + 15 - HALFW) && (c0 + 31 <= q0 + HALFW);
    if (full) {
#pragma unroll
      for (int r = 0; r < 4; ++r) { p0[r] = fexp(s0[r]); p1[r] = fexp(s1[r]); }
    } else {
      int d0 = c0 + 4 * g - qi + HALFW;
#pragma unroll
      for (int r = 0; r < 4; ++r) {
        p0[r] = ((u32)(d0 + r) <= 2u * HALFW) ? fexp(s0[r]) : 0.f;
        p1[r] = ((u32)(d0 + 16 + r) <= 2u * HALFW) ? fexp(s1[r]) : 0.f;
      }
    }
    lacc += ((p0[0] + p0[1]) + (p0[2] + p0[3])) + ((p1[0] + p1[1]) + (p1[2] + p1[3]));
    u32 pk0 = cvtpk(p0[0], p0[1]), pk1 = cvtpk(p0[2], p0[3]);
    u32 pk2 = cvtpk(p1[0], p1[1]), pk3 = cvtpk(p1[2], p1[3]);
    u32 a0 = (u32)__builtin_amdgcn_ds_bpermute(l0b, (int)pk0);
    u32 b0 = (u32)__builtin_amdgcn_ds_bpermute(l0b, (int)pk2);
    u32 a1 = (u32)__builtin_amdgcn_ds_bpermute(l0b, (int)pk1);
    u32 b1 = (u32)__builtin_amdgcn_ds_bpermute(l0b, (int)pk3);
    u32 a2 = (u32)__builtin_amdgcn_ds_bpermute(l1b, (int)pk0);
    u32 b2 = (u32)__builtin_amdgcn_ds_bpermute(l1b, (int)pk2);
    u32 a3 = (u32)__builtin_amdgcn_ds_bpermute(l1b, (int)pk1);
    u32 b3 = (u32)__builtin_amdgcn_ds_bpermute(l1b, (int)pk3);
    union { bfrag f; u32 w[4]; } pb;
    pb.w[0] = hi5 ? b0 : a0;
    pb.w[1] = hi5 ? b1 : a1;
    pb.w[2] = hi5 ? b2 : a2;
    pb.w[3] = hi5 ? b3 : a3;
    __builtin_amdgcn_s_setprio(1);
#pragma unroll
    for (int n = 0; n < 4; ++n) {
      bfrag vf = *reinterpret_cast<const bfrag*>(&Vb[(size_t)(n * 16 + col) * S_LEN + c0 + 8 * g]);
      octx[n] = __builtin_amdgcn_mfma_f32_16x16x32_bf16(vf, pb.f, octx[n], 0, 0, 0);
    }
    __builtin_amdgcn_s_setprio(0);
  }
  float l = lacc + __shfl_xor(lacc, 16);
  l += __shfl_xor(l, 32);
  float linv = __builtin_amdgcn_rcpf(l);
  u16* cb = ctx + (size_t)b * S_LEN * DMODEL + (size_t)(q0 + col) * DMODEL + h * HD;
#pragma unroll
  for (int n = 0; n < 4; ++n) {
    uint2 o;
    o.x = cvtpk(octx[n][0] * linv, octx[n][1] * linv);
    o.y = cvtpk(octx[n][2] * linv, octx[n][3] * linv);
    *reinterpret_cast<uint2*>(cb + n * 16 + 4 * g) = o;
  }
}

extern "C" void kernel_launch(void* const* d_in, const int* in_sizes, int n_in,
                              void* d_out, int out_size, void* d_ws, size_t ws_size,
                              hipStream_t stream) {
  (void)in_sizes; (void)n_in; (void)out_size; (void)ws_size;
  const float* x  = (const float*)d_in[0];
  const float* Wq = (const float*)d_in[1];
  const float* Wk = (const float*)d_in[2];
  const float* Wv = (const float*)d_in[3];
  const float* Wo = (const float*)d_in[4];
  char* ws = (char*)d_ws;
  u16*    xb     = (u16*)(ws + 0);          //  8,388,608
  u16*    Wcat_t = (u16*)(ws + 8388608);    //  3,145,728  (1536 x 1024)
  u16*    Wo_t   = (u16*)(ws + 11534336);   //  2,097,152
  u16*    Qr     = (u16*)(ws + 13631488);   //  8,388,608  (b,h,s,64)
  u16*    Kr     = (u16*)(ws + 22020096);   //  2,097,152  (b,kv,s,64)
  u16*    Vt     = (u16*)(ws + 24117248);   //  2,097,152  (b,kv,64,s)
  u16*    ctxb   = (u16*)(ws + 26214400);   //  8,388,608
  float2* csT    = (float2*)(ws + 34603008);//    524,288  -> total 35,127,296 B

  rope_table_k<<<256, 256, 0, stream>>>(csT);
  cast_x_k<<<4096, 256, 0, stream>>>(x, xb);
  transpose_cast_all_k<<<dim3(32, 80), dim3(32, 8), 0, stream>>>(Wq, Wk, Wv, Wo, Wcat_t, Wo_t);
  gemm_qkv_k<<<dim3(12, 32), 256, 0, stream>>>(xb, Wcat_t, csT, Qr, Kr, Vt);
  attn_k<<<1024, 256, 0, stream>>>(Qr, Kr, Vt, ctxb);
  gemm_bt_k<<<dim3(8, 32), 256, 0, stream>>>(ctxb, Wo_t, (float*)d_out, 1024);
}

// Round 4
// 85.691 us; speedup vs baseline: 1.4917x; 1.2816x over previous
//
#include <hip/hip_runtime.h>

typedef unsigned short u16;
typedef unsigned int u32;
typedef __attribute__((ext_vector_type(8))) short bfrag;   // 8 x bf16 (4 VGPRs)
typedef __attribute__((ext_vector_type(4))) float f32x4;

#define S_LEN 2048
#define DMODEL 1024
#define NHQ 16
#define NHKV 4
#define HD 64
#define HALFW 128
#define ROWS 4096   // B*S
#define QSCALE 0.1803368801111244f   // 0.125 * log2(e)

__device__ __forceinline__ u16 f2b(float f) {
  u32 x = __float_as_uint(f);
  return (u16)((x + 0x7fffu + ((x >> 16) & 1u)) >> 16);  // RNE
}

__device__ __forceinline__ u32 cvtpk(float lo, float hi) {
  u32 r;
  asm("v_cvt_pk_bf16_f32 %0, %1, %2" : "=v"(r) : "v"(lo), "v"(hi));
  return r;
}

__device__ __forceinline__ float fexp(float x) {  // 2^x
  float r;
  asm("v_exp_f32 %0, %1" : "=v"(r) : "v"(x));
  return r;
}

// ---------------- kernel 1: cast x -> bf16 ----------------
__global__ void cast_x_k(const float* __restrict__ x, u16* __restrict__ xb) {
  int i = (blockIdx.x * blockDim.x + threadIdx.x) * 4;
  float4 v = *reinterpret_cast<const float4*>(x + i);
  uint2 p;
  p.x = (u32)f2b(v.x) | ((u32)f2b(v.y) << 16);
  p.y = (u32)f2b(v.z) | ((u32)f2b(v.w) << 16);
  *reinterpret_cast<uint2*>(xb + i) = p;
}

// ---------------- kernel 2: transpose-cast all weights + RoPE table, one launch ----------------
// grid.y: 0..31 Wq; 32..39 Wk; 40..47 Wv; 48..79 Wo; 80..87 RoPE table.
__global__ void transpose_cast_all_k(const float* __restrict__ Wq, const float* __restrict__ Wk,
                                     const float* __restrict__ Wv, const float* __restrict__ Wo,
                                     u16* __restrict__ Wcat_t, u16* __restrict__ Wo_t,
                                     float2* __restrict__ csT) {
  __shared__ float tile[32][33];
  int y = blockIdx.y;
  if (y >= 80) {  // RoPE table: 8 y * 32 bx * 256 t = 65536 entries
    int tid = threadIdx.y * 32 + threadIdx.x;
    int idx = ((y - 80) * 32 + blockIdx.x) * 256 + tid;
    int s = idx >> 5, i = idx & 31;
    double inv = pow(10000.0, -(double)(2 * i) / 64.0);
    double ang = (double)s * inv;
    csT[idx] = make_float2((float)cos(ang), (float)sin(ang));
    return;
  }
  int k0 = blockIdx.x * 32;
  const float* src; u16* dst; int ncols, n0;
  if (y < 32)      { src = Wq; dst = Wcat_t;                       ncols = 1024; n0 = y * 32; }
  else if (y < 40) { src = Wk; dst = Wcat_t + (size_t)1024 * 1024; ncols = 256;  n0 = (y - 32) * 32; }
  else if (y < 48) { src = Wv; dst = Wcat_t + (size_t)1280 * 1024; ncols = 256;  n0 = (y - 40) * 32; }
  else             { src = Wo; dst = Wo_t;                         ncols = 1024; n0 = (y - 48) * 32; }
  int tx = threadIdx.x, ty = threadIdx.y;  // 32 x 8
#pragma unroll
  for (int j = 0; j < 4; ++j)
    tile[ty + 8 * j][tx] = src[(size_t)(k0 + ty + 8 * j) * ncols + n0 + tx];
  __syncthreads();
#pragma unroll
  for (int j = 0; j < 4; ++j)
    dst[(size_t)(n0 + ty + 8 * j) * 1024 + k0 + tx] = f2b(tile[tx][ty + 8 * j]);
}

// ---------------- kernel 3: QKV GEMM (128x64 tile) + fused RoPE/scatter epilogue ----------------
// 768 blocks = 3.0/CU. 4 waves as 2x2; wave computes 64x32 (acc[4][2]).
__global__ __launch_bounds__(256) void gemm_qkv_k(const u16* __restrict__ A, const u16* __restrict__ Bt,
                                                  const float2* __restrict__ csT,
                                                  u16* __restrict__ Qr, u16* __restrict__ Kr,
                                                  u16* __restrict__ Vt) {
  __shared__ u16 lds_a[128 * 32];
  __shared__ u16 lds_b[64 * 32];
  int t = threadIdx.x;
  int wave = t >> 6, lane = t & 63;
  int g = lane >> 4, col = lane & 15;
  int m0 = blockIdx.y * 128, n0 = blockIdx.x * 64;
  int wm = wave >> 1, wn = wave & 1;
  int srow = t >> 2, scol = (t & 3) * 8;
  const u16* Abase = A + (size_t)(m0 + srow) * 1024 + scol;
  const u16* Bbase = Bt + (size_t)(n0 + srow) * 1024 + scol;
  u16* la = lds_a + wave * 512;  // wave-uniform base; HW adds lane*16B
  u16* lb = lds_b + wave * 512;
  f32x4 acc[4][2] = {};
  for (int kt = 0; kt < 32; ++kt) {
    int k0 = kt * 32;
#pragma unroll
    for (int r = 0; r < 2; ++r)
      __builtin_amdgcn_global_load_lds(
          (const __attribute__((address_space(1))) u32*)(Abase + (size_t)r * 64 * 1024 + k0),
          (__attribute__((address_space(3))) u32*)(la + r * 2048), 16, 0, 0);
    __builtin_amdgcn_global_load_lds(
        (const __attribute__((address_space(1))) u32*)(Bbase + k0),
        (__attribute__((address_space(3))) u32*)lb, 16, 0, 0);
    __syncthreads();
    bfrag af[4], bf[2];
#pragma unroll
    for (int mi = 0; mi < 4; ++mi)
      af[mi] = *reinterpret_cast<const bfrag*>(&lds_a[(wm * 64 + mi * 16 + col) * 32 + 8 * g]);
#pragma unroll
    for (int ni = 0; ni < 2; ++ni)
      bf[ni] = *reinterpret_cast<const bfrag*>(&lds_b[(wn * 32 + ni * 16 + col) * 32 + 8 * g]);
#pragma unroll
    for (int mi = 0; mi < 4; ++mi)
#pragma unroll
      for (int ni = 0; ni < 2; ++ni)
        acc[mi][ni] = __builtin_amdgcn_mfma_f32_16x16x32_bf16(af[mi], bf[ni], acc[mi][ni], 0, 0, 0);
    __syncthreads();
  }
  bool odd = (col & 1) != 0;
#pragma unroll
  for (int mi = 0; mi < 4; ++mi)
#pragma unroll
    for (int ni = 0; ni < 2; ++ni) {
      int cg = n0 + wn * 32 + ni * 16 + col;
      int rowbase = m0 + wm * 64 + mi * 16 + g * 4;
      if (cg < 1024) {  // ---- Q: RoPE + QSCALE ----
        int hq = cg >> 6, d = cg & 63, i = d >> 1;
        u16* dst = Qr + ((size_t)((rowbase >> 11) * NHQ + hq) * S_LEN + (rowbase & 2047)) * HD + d;
#pragma unroll
        for (int r = 0; r < 4; ++r) {
          int s = (rowbase + r) & 2047;
          float v = acc[mi][ni][r];
          float pv = __shfl_xor(v, 1);
          float2 cs = csT[s * 32 + i];
          float o = odd ? (pv * cs.y + v * cs.x) : (v * cs.x - pv * cs.y);
          dst[(size_t)r * HD] = f2b(o * QSCALE);
        }
      } else if (cg < 1280) {  // ---- K: RoPE ----
        int j = cg - 1024;
        int kh = j >> 6, d = j & 63, i = d >> 1;
        u16* dst = Kr + ((size_t)((rowbase >> 11) * NHKV + kh) * S_LEN + (rowbase & 2047)) * HD + d;
#pragma unroll
        for (int r = 0; r < 4; ++r) {
          int s = (rowbase + r) & 2047;
          float v = acc[mi][ni][r];
          float pv = __shfl_xor(v, 1);
          float2 cs = csT[s * 32 + i];
          float o = odd ? (pv * cs.y + v * cs.x) : (v * cs.x - pv * cs.y);
          dst[(size_t)r * HD] = f2b(o);
        }
      } else {  // ---- V: transpose to (b,kv,64,S) ----
        int j = cg - 1280;
        int kh = j >> 6, d = j & 63;
        int b = rowbase >> 11, s0 = rowbase & 2047;
        uint2 o;
        o.x = (u32)f2b(acc[mi][ni][0]) | ((u32)f2b(acc[mi][ni][1]) << 16);
        o.y = (u32)f2b(acc[mi][ni][2]) | ((u32)f2b(acc[mi][ni][3]) << 16);
        *reinterpret_cast<uint2*>(Vt + ((size_t)(b * NHKV + kh) * HD + d) * S_LEN + s0) = o;
      }
    }
}

// ---------------- kernel 4: out-proj GEMM (128x64 tile), C fp32 ----------------
__global__ __launch_bounds__(256) void gemm_bt_k(const u16* __restrict__ A, const u16* __restrict__ Bt,
                                                 float* __restrict__ C, int N) {
  __shared__ u16 lds_a[128 * 32];
  __shared__ u16 lds_b[64 * 32];
  int t = threadIdx.x;
  int wave = t >> 6, lane = t & 63;
  int g = lane >> 4, col = lane & 15;
  int m0 = blockIdx.y * 128, n0 = blockIdx.x * 64;
  int wm = wave >> 1, wn = wave & 1;
  int srow = t >> 2, scol = (t & 3) * 8;
  const u16* Abase = A + (size_t)(m0 + srow) * 1024 + scol;
  const u16* Bbase = Bt + (size_t)(n0 + srow) * 1024 + scol;
  u16* la = lds_a + wave * 512;
  u16* lb = lds_b + wave * 512;
  f32x4 acc[4][2] = {};
  for (int kt = 0; kt < 32; ++kt) {
    int k0 = kt * 32;
#pragma unroll
    for (int r = 0; r < 2; ++r)
      __builtin_amdgcn_global_load_lds(
          (const __attribute__((address_space(1))) u32*)(Abase + (size_t)r * 64 * 1024 + k0),
          (__attribute__((address_space(3))) u32*)(la + r * 2048), 16, 0, 0);
    __builtin_amdgcn_global_load_lds(
        (const __attribute__((address_space(1))) u32*)(Bbase + k0),
        (__attribute__((address_space(3))) u32*)lb, 16, 0, 0);
    __syncthreads();
    bfrag af[4], bf[2];
#pragma unroll
    for (int mi = 0; mi < 4; ++mi)
      af[mi] = *reinterpret_cast<const bfrag*>(&lds_a[(wm * 64 + mi * 16 + col) * 32 + 8 * g]);
#pragma unroll
    for (int ni = 0; ni < 2; ++ni)
      bf[ni] = *reinterpret_cast<const bfrag*>(&lds_b[(wn * 32 + ni * 16 + col) * 32 + 8 * g]);
#pragma unroll
    for (int mi = 0; mi < 4; ++mi)
#pragma unroll
      for (int ni = 0; ni < 2; ++ni)
        acc[mi][ni] = __builtin_amdgcn_mfma_f32_16x16x32_bf16(af[mi], bf[ni], acc[mi][ni], 0, 0, 0);
    __syncthreads();
  }
#pragma unroll
  for (int mi = 0; mi < 4; ++mi)
#pragma unroll
    for (int ni = 0; ni < 2; ++ni) {
      int row = m0 + wm * 64 + mi * 16 + g * 4;
      int cc = n0 + wn * 32 + ni * 16 + col;
#pragma unroll
      for (int r = 0; r < 4; ++r)
        C[(size_t)(row + r) * N + cc] = acc[mi][ni][r];
    }
}

// ---------------- kernel 5: sliding-window flash attention, 32 q-rows/wave ----------------
// 512 blocks x 4 waves; wave owns q0..q0+31 as two 16-col q-groups sharing K/V loads.
__global__ __launch_bounds__(256) void attn_k(const u16* __restrict__ Qr, const u16* __restrict__ Kr,
                                              const u16* __restrict__ Vt, u16* __restrict__ ctx) {
  int bid = blockIdx.x;
  int qblk = bid & 15, h = (bid >> 4) & 15, b = bid >> 8;
  int wave = threadIdx.x >> 6, lane = threadIdx.x & 63;
  int g = lane >> 4, col = lane & 15;
  int kv = h >> 2;
  int q0 = qblk * 128 + wave * 32;
  const u16* Qb = Qr + (size_t)(b * NHQ + h) * S_LEN * HD;
  const u16* Kb = Kr + (size_t)(b * NHKV + kv) * S_LEN * HD;
  const u16* Vb = Vt + (size_t)(b * NHKV + kv) * HD * S_LEN;
  bfrag qf[2][2];
#pragma unroll
  for (int qg = 0; qg < 2; ++qg) {
    qf[qg][0] = *reinterpret_cast<const bfrag*>(&Qb[(size_t)(q0 + qg * 16 + col) * HD + 8 * g]);
    qf[qg][1] = *reinterpret_cast<const bfrag*>(&Qb[(size_t)(q0 + qg * 16 + col) * HD + 32 + 8 * g]);
  }
  f32x4 octx[2][4] = {};
  float lacc[2] = {0.f, 0.f};
  int qi[2] = {q0 + col, q0 + 16 + col};
  bool hi5 = (threadIdx.x & 32) != 0;
  int l0b = (col + ((lane >> 4) & 1) * 32) << 2;
  int l1b = l0b + 64;
  int lo = q0 - HALFW; if (lo < 0) lo = 0; lo &= ~31;
  int hi = q0 + 32 + HALFW; if (hi > S_LEN) hi = S_LEN;
  for (int c0 = lo; c0 < hi; c0 += 32) {
    f32x4 s[2][2] = {};   // [qg][kt]
    __builtin_amdgcn_s_setprio(1);
#pragma unroll
    for (int kt = 0; kt < 2; ++kt)
#pragma unroll
      for (int dh = 0; dh < 2; ++dh) {
        bfrag kf = *reinterpret_cast<const bfrag*>(&Kb[(size_t)(c0 + kt * 16 + col) * HD + 32 * dh + 8 * g]);
        s[0][kt] = __builtin_amdgcn_mfma_f32_16x16x32_bf16(kf, qf[0][dh], s[0][kt], 0, 0, 0);
        s[1][kt] = __builtin_amdgcn_mfma_f32_16x16x32_bf16(kf, qf[1][dh], s[1][kt], 0, 0, 0);
      }
    __builtin_amdgcn_s_setprio(0);
    bool full = (c0 >= q0 + 31 - HALFW) && (c0 + 31 <= q0 + HALFW);
    union { bfrag f; u32 w[4]; } pb[2];
#pragma unroll
    for (int qg = 0; qg < 2; ++qg) {
      float p0[4], p1[4];
      if (full) {
#pragma unroll
        for (int r = 0; r < 4; ++r) { p0[r] = fexp(s[qg][0][r]); p1[r] = fexp(s[qg][1][r]); }
      } else {
        int d0 = c0 + 4 * g - qi[qg] + HALFW;
#pragma unroll
        for (int r = 0; r < 4; ++r) {
          p0[r] = ((u32)(d0 + r) <= 2u * HALFW) ? fexp(s[qg][0][r]) : 0.f;
          p1[r] = ((u32)(d0 + 16 + r) <= 2u * HALFW) ? fexp(s[qg][1][r]) : 0.f;
        }
      }
      lacc[qg] += ((p0[0] + p0[1]) + (p0[2] + p0[3])) + ((p1[0] + p1[1]) + (p1[2] + p1[3]));
      u32 pk0 = cvtpk(p0[0], p0[1]), pk1 = cvtpk(p0[2], p0[3]);
      u32 pk2 = cvtpk(p1[0], p1[1]), pk3 = cvtpk(p1[2], p1[3]);
      u32 a0 = (u32)__builtin_amdgcn_ds_bpermute(l0b, (int)pk0);
      u32 b0 = (u32)__builtin_amdgcn_ds_bpermute(l0b, (int)pk2);
      u32 a1 = (u32)__builtin_amdgcn_ds_bpermute(l0b, (int)pk1);
      u32 b1 = (u32)__builtin_amdgcn_ds_bpermute(l0b, (int)pk3);
      u32 a2 = (u32)__builtin_amdgcn_ds_bpermute(l1b, (int)pk0);
      u32 b2 = (u32)__builtin_amdgcn_ds_bpermute(l1b, (int)pk2);
      u32 a3 = (u32)__builtin_amdgcn_ds_bpermute(l1b, (int)pk1);
      u32 b3 = (u32)__builtin_amdgcn_ds_bpermute(l1b, (int)pk3);
      pb[qg].w[0] = hi5 ? b0 : a0;
      pb[qg].w[1] = hi5 ? b1 : a1;
      pb[qg].w[2] = hi5 ? b2 : a2;
      pb[qg].w[3] = hi5 ? b3 : a3;
    }
    __builtin_amdgcn_s_setprio(1);
#pragma unroll
    for (int n = 0; n < 4; ++n) {
      bfrag vf = *reinterpret_cast<const bfrag*>(&Vb[(size_t)(n * 16 + col) * S_LEN + c0 + 8 * g]);
      octx[0][n] = __builtin_amdgcn_mfma_f32_16x16x32_bf16(vf, pb[0].f, octx[0][n], 0, 0, 0);
      octx[1][n] = __builtin_amdgcn_mfma_f32_16x16x32_bf16(vf, pb[1].f, octx[1][n], 0, 0, 0);
    }
    __builtin_amdgcn_s_setprio(0);
  }
#pragma unroll
  for (int qg = 0; qg < 2; ++qg) {
    float l = lacc[qg] + __shfl_xor(lacc[qg], 16);
    l += __shfl_xor(l, 32);
    float linv = __builtin_amdgcn_rcpf(l);
    u16* cb = ctx + (size_t)b * S_LEN * DMODEL + (size_t)(q0 + qg * 16 + col) * DMODEL + h * HD;
#pragma unroll
    for (int n = 0; n < 4; ++n) {
      uint2 o;
      o.x = cvtpk(octx[qg][n][0] * linv, octx[qg][n][1] * linv);
      o.y = cvtpk(octx[qg][n][2] * linv, octx[qg][n][3] * linv);
      *reinterpret_cast<uint2*>(cb + n * 16 + 4 * g) = o;
    }
  }
}

extern "C" void kernel_launch(void* const* d_in, const int* in_sizes, int n_in,
                              void* d_out, int out_size, void* d_ws, size_t ws_size,
                              hipStream_t stream) {
  (void)in_sizes; (void)n_in; (void)out_size; (void)ws_size;
  const float* x  = (const float*)d_in[0];
  const float* Wq = (const float*)d_in[1];
  const float* Wk = (const float*)d_in[2];
  const float* Wv = (const float*)d_in[3];
  const float* Wo = (const float*)d_in[4];
  char* ws = (char*)d_ws;
  u16*    xb     = (u16*)(ws + 0);          //  8,388,608
  u16*    Wcat_t = (u16*)(ws + 8388608);    //  3,145,728  (1536 x 1024)
  u16*    Wo_t   = (u16*)(ws + 11534336);   //  2,097,152
  u16*    Qr     = (u16*)(ws + 13631488);   //  8,388,608  (b,h,s,64)
  u16*    Kr     = (u16*)(ws + 22020096);   //  2,097,152  (b,kv,s,64)
  u16*    Vt     = (u16*)(ws + 24117248);   //  2,097,152  (b,kv,64,s)
  u16*    ctxb   = (u16*)(ws + 26214400);   //  8,388,608
  float2* csT    = (float2*)(ws + 34603008);//    524,288  -> total 35,127,296 B

  cast_x_k<<<4096, 256, 0, stream>>>(x, xb);
  transpose_cast_all_k<<<dim3(32, 88), dim3(32, 8), 0, stream>>>(Wq, Wk, Wv, Wo, Wcat_t, Wo_t, csT);
  gemm_qkv_k<<<dim3(24, 32), 256, 0, stream>>>(xb, Wcat_t, csT, Qr, Kr, Vt);
  attn_k<<<512, 256, 0, stream>>>(Qr, Kr, Vt, ctxb);
  gemm_bt_k<<<dim3(16, 32), 256, 0, stream>>>(ctxb, Wo_t, (float*)d_out, 1024);
}

// Round 6
// 75.696 us; speedup vs baseline: 1.6887x; 1.1320x over previous
//
#include <hip/hip_runtime.h>

typedef unsigned short u16;
typedef unsigned int u32;
typedef __attribute__((ext_vector_type(8))) short bfrag;   // 8 x bf16 (4 VGPRs)
typedef __attribute__((ext_vector_type(4))) float f32x4;

#define S_LEN 2048
#define DMODEL 1024
#define NHQ 16
#define NHKV 4
#define HD 64
#define HALFW 128
#define ROWS 4096   // B*S
#define QSCALE 0.1803368801111244f   // 0.125 * log2(e)

__device__ __forceinline__ u16 f2b(float f) {
  u32 x = __float_as_uint(f);
  return (u16)((x + 0x7fffu + ((x >> 16) & 1u)) >> 16);  // RNE
}

__device__ __forceinline__ u32 cvtpk(float lo, float hi) {
  u32 r;
  asm("v_cvt_pk_bf16_f32 %0, %1, %2" : "=v"(r) : "v"(lo), "v"(hi));
  return r;
}

__device__ __forceinline__ float fexp(float x) {  // 2^x
  float r;
  asm("v_exp_f32 %0, %1" : "=v"(r) : "v"(x));
  return r;
}

// ---------------- kernel 1: prep — weights transpose-cast + RoPE table + x cast ----------------
// grid.y: 0..31 Wq; 32..39 Wk; 40..47 Wv; 48..79 Wo; 80..87 RoPE table; 88..215 cast x.
__global__ void prep_k(const float* __restrict__ x, const float* __restrict__ Wq,
                       const float* __restrict__ Wk, const float* __restrict__ Wv,
                       const float* __restrict__ Wo, u16* __restrict__ xb,
                       u16* __restrict__ Wcat_t, u16* __restrict__ Wo_t,
                       float2* __restrict__ csT) {
  __shared__ float tile[32][33];
  int y = blockIdx.y;
  int tid = threadIdx.y * 32 + threadIdx.x;
  if (y >= 88) {  // cast x -> bf16: 128 y * 32 bx blocks, 1024 elems each
    int i = (((y - 88) * 32 + blockIdx.x) * 256 + tid) * 4;
    float4 v = *reinterpret_cast<const float4*>(x + i);
    uint2 p;
    p.x = (u32)f2b(v.x) | ((u32)f2b(v.y) << 16);
    p.y = (u32)f2b(v.z) | ((u32)f2b(v.w) << 16);
    *reinterpret_cast<uint2*>(xb + i) = p;
    return;
  }
  if (y >= 80) {  // RoPE table: 8 y * 32 bx * 256 t = 65536 entries
    int idx = ((y - 80) * 32 + blockIdx.x) * 256 + tid;
    int s = idx >> 5, i = idx & 31;
    double inv = pow(10000.0, -(double)(2 * i) / 64.0);
    double ang = (double)s * inv;
    csT[idx] = make_float2((float)cos(ang), (float)sin(ang));
    return;
  }
  int k0 = blockIdx.x * 32;
  const float* src; u16* dst; int ncols, n0;
  if (y < 32)      { src = Wq; dst = Wcat_t;                       ncols = 1024; n0 = y * 32; }
  else if (y < 40) { src = Wk; dst = Wcat_t + (size_t)1024 * 1024; ncols = 256;  n0 = (y - 32) * 32; }
  else if (y < 48) { src = Wv; dst = Wcat_t + (size_t)1280 * 1024; ncols = 256;  n0 = (y - 40) * 32; }
  else             { src = Wo; dst = Wo_t;                         ncols = 1024; n0 = (y - 48) * 32; }
  int tx = threadIdx.x, ty = threadIdx.y;  // 32 x 8
#pragma unroll
  for (int j = 0; j < 4; ++j)
    tile[ty + 8 * j][tx] = src[(size_t)(k0 + ty + 8 * j) * ncols + n0 + tx];
  __syncthreads();
#pragma unroll
  for (int j = 0; j < 4; ++j)
    dst[(size_t)(n0 + ty + 8 * j) * 1024 + k0 + tx] = f2b(tile[tx][ty + 8 * j]);
}

// ======== shared GEMM core: 128x64 tile, BK=64, double-buffered, XOR-swizzled LDS ========
// LDS A: [2][128][64] linear dest for global_load_lds; element (row, slot) lands at
// row*64 + (slot^(row&7))*8 because the GLOBAL source slot is inverse-swizzled.
// Read side applies the same XOR -> 2-way bank aliasing only (free, m136).
__device__ __forceinline__ void gemm_core(const u16* __restrict__ A, const u16* __restrict__ Bt,
                                          int m0, int n0, int wave, int lane,
                                          f32x4 acc[4][2]) {
  __shared__ u16 lds_a[2 * 128 * 64];
  __shared__ u16 lds_b[2 * 64 * 64];
  int t = wave * 64 + lane;
  int g = lane >> 4, col = lane & 15;
  int wm = wave >> 1, wn = wave & 1;
  int r8 = t >> 3, slot = (t & 7) ^ (r8 & 7);
  const u16* Ab = A + (size_t)(m0 + r8) * 1024 + slot * 8;
  const u16* Bb = Bt + (size_t)(n0 + r8) * 1024 + slot * 8;
  int c7 = col & 7;
  int aoff0 = (wm * 64 + col) * 64;
  int boff0 = (wn * 32 + col) * 64;
  // prologue: stage tile 0 into buf 0
#pragma unroll
  for (int j = 0; j < 4; ++j)
    __builtin_amdgcn_global_load_lds(
        (const __attribute__((address_space(1))) u32*)(Ab + (size_t)j * 32768),
        (__attribute__((address_space(3))) u32*)(lds_a + j * 2048 + wave * 512), 16, 0, 0);
#pragma unroll
  for (int j = 0; j < 2; ++j)
    __builtin_amdgcn_global_load_lds(
        (const __attribute__((address_space(1))) u32*)(Bb + (size_t)j * 32768),
        (__attribute__((address_space(3))) u32*)(lds_b + j * 2048 + wave * 512), 16, 0, 0);
  __syncthreads();
  for (int kt = 0; kt < 16; ++kt) {
    int cur = kt & 1;
    if (kt < 15) {  // stage tile kt+1 into buf cur^1 (overlaps with compute below)
      int ko = (kt + 1) * 64;
      u16* la = lds_a + (cur ^ 1) * 8192;
      u16* lb = lds_b + (cur ^ 1) * 4096;
#pragma unroll
      for (int j = 0; j < 4; ++j)
        __builtin_amdgcn_global_load_lds(
            (const __attribute__((address_space(1))) u32*)(Ab + (size_t)j * 32768 + ko),
            (__attribute__((address_space(3))) u32*)(la + j * 2048 + wave * 512), 16, 0, 0);
#pragma unroll
      for (int j = 0; j < 2; ++j)
        __builtin_amdgcn_global_load_lds(
            (const __attribute__((address_space(1))) u32*)(Bb + (size_t)j * 32768 + ko),
            (__attribute__((address_space(3))) u32*)(lb + j * 2048 + wave * 512), 16, 0, 0);
    }
    const u16* la = lds_a + cur * 8192;
    const u16* lb = lds_b + cur * 4096;
#pragma unroll
    for (int sub = 0; sub < 2; ++sub) {
      int sa = ((sub * 4 + g) ^ c7) * 8;
      bfrag af[4], bf[2];
#pragma unroll
      for (int mi = 0; mi < 4; ++mi)
        af[mi] = *reinterpret_cast<const bfrag*>(&la[aoff0 + mi * 1024 + sa]);
#pragma unroll
      for (int ni = 0; ni < 2; ++ni)
        bf[ni] = *reinterpret_cast<const bfrag*>(&lb[boff0 + ni * 1024 + sa]);
#pragma unroll
      for (int mi = 0; mi < 4; ++mi)
#pragma unroll
        for (int ni = 0; ni < 2; ++ni)
          acc[mi][ni] = __builtin_amdgcn_mfma_f32_16x16x32_bf16(af[mi], bf[ni], acc[mi][ni], 0, 0, 0);
    }
    if (kt < 15) __syncthreads();
  }
}

// ---------------- kernel 2: QKV GEMM + fused RoPE/scatter epilogue ----------------
__global__ __launch_bounds__(256) void gemm_qkv_k(const u16* __restrict__ A, const u16* __restrict__ Bt,
                                                  const float2* __restrict__ csT,
                                                  u16* __restrict__ Qr, u16* __restrict__ Kr,
                                                  u16* __restrict__ Vt) {
  int t = threadIdx.x;
  int wave = t >> 6, lane = t & 63;
  int g = lane >> 4, col = lane & 15;
  int m0 = blockIdx.y * 128, n0 = blockIdx.x * 64;
  int wm = wave >> 1, wn = wave & 1;
  f32x4 acc[4][2] = {};
  gemm_core(A, Bt, m0, n0, wave, lane, acc);
  bool odd = (col & 1) != 0;
#pragma unroll
  for (int mi = 0; mi < 4; ++mi)
#pragma unroll
    for (int ni = 0; ni < 2; ++ni) {
      int cg = n0 + wn * 32 + ni * 16 + col;
      int rowbase = m0 + wm * 64 + mi * 16 + g * 4;
      if (cg < 1024) {  // Q: RoPE + QSCALE
        int hq = cg >> 6, d = cg & 63, i = d >> 1;
        u16* dst = Qr + ((size_t)((rowbase >> 11) * NHQ + hq) * S_LEN + (rowbase & 2047)) * HD + d;
#pragma unroll
        for (int r = 0; r < 4; ++r) {
          int s = (rowbase + r) & 2047;
          float v = acc[mi][ni][r];
          float pv = __shfl_xor(v, 1);
          float2 cs = csT[s * 32 + i];
          float o = odd ? (pv * cs.y + v * cs.x) : (v * cs.x - pv * cs.y);
          dst[(size_t)r * HD] = f2b(o * QSCALE);
        }
      } else if (cg < 1280) {  // K: RoPE
        int j = cg - 1024;
        int kh = j >> 6, d = j & 63, i = d >> 1;
        u16* dst = Kr + ((size_t)((rowbase >> 11) * NHKV + kh) * S_LEN + (rowbase & 2047)) * HD + d;
#pragma unroll
        for (int r = 0; r < 4; ++r) {
          int s = (rowbase + r) & 2047;
          float v = acc[mi][ni][r];
          float pv = __shfl_xor(v, 1);
          float2 cs = csT[s * 32 + i];
          float o = odd ? (pv * cs.y + v * cs.x) : (v * cs.x - pv * cs.y);
          dst[(size_t)r * HD] = f2b(o);
        }
      } else {  // V: transpose to (b,kv,64,S)
        int j = cg - 1280;
        int kh = j >> 6, d = j & 63;
        int b = rowbase >> 11, s0 = rowbase & 2047;
        uint2 o;
        o.x = (u32)f2b(acc[mi][ni][0]) | ((u32)f2b(acc[mi][ni][1]) << 16);
        o.y = (u32)f2b(acc[mi][ni][2]) | ((u32)f2b(acc[mi][ni][3]) << 16);
        *reinterpret_cast<uint2*>(Vt + ((size_t)(b * NHKV + kh) * HD + d) * S_LEN + s0) = o;
      }
    }
}

// ---------------- kernel 3: out-proj GEMM, C fp32 ----------------
__global__ __launch_bounds__(256) void gemm_bt_k(const u16* __restrict__ A, const u16* __restrict__ Bt,
                                                 float* __restrict__ C, int N) {
  int t = threadIdx.x;
  int wave = t >> 6, lane = t & 63;
  int g = lane >> 4, col = lane & 15;
  int m0 = blockIdx.y * 128, n0 = blockIdx.x * 64;
  int wm = wave >> 1, wn = wave & 1;
  f32x4 acc[4][2] = {};
  gemm_core(A, Bt, m0, n0, wave, lane, acc);
#pragma unroll
  for (int mi = 0; mi < 4; ++mi)
#pragma unroll
    for (int ni = 0; ni < 2; ++ni) {
      int row = m0 + wm * 64 + mi * 16 + g * 4;
      int cc = n0 + wn * 32 + ni * 16 + col;
#pragma unroll
      for (int r = 0; r < 4; ++r)
        C[(size_t)(row + r) * N + cc] = acc[mi][ni][r];
    }
}

// ---------------- kernel 4: sliding-window flash attention, 32 q-rows/wave ----------------
__global__ __launch_bounds__(256) void attn_k(const u16* __restrict__ Qr, const u16* __restrict__ Kr,
                                              const u16* __restrict__ Vt, u16* __restrict__ ctx) {
  int bid = blockIdx.x;
  int qblk = bid & 15, h = (bid >> 4) & 15, b = bid >> 8;
  int wave = threadIdx.x >> 6, lane = threadIdx.x & 63;
  int g = lane >> 4, col = lane & 15;
  int kv = h >> 2;
  int q0 = qblk * 128 + wave * 32;
  const u16* Qb = Qr + (size_t)(b * NHQ + h) * S_LEN * HD;
  const u16* Kb = Kr + (size_t)(b * NHKV + kv) * S_LEN * HD;
  const u16* Vb = Vt + (size_t)(b * NHKV + kv) * HD * S_LEN;
  bfrag qf[2][2];
#pragma unroll
  for (int qg = 0; qg < 2; ++qg) {
    qf[qg][0] = *reinterpret_cast<const bfrag*>(&Qb[(size_t)(q0 + qg * 16 + col) * HD + 8 * g]);
    qf[qg][1] = *reinterpret_cast<const bfrag*>(&Qb[(size_t)(q0 + qg * 16 + col) * HD + 32 + 8 * g]);
  }
  f32x4 octx[2][4] = {};
  float lacc[2] = {0.f, 0.f};
  int qi[2] = {q0 + col, q0 + 16 + col};
  bool hi5 = (threadIdx.x & 32) != 0;
  int l0b = (col + ((lane >> 4) & 1) * 32) << 2;
  int l1b = l0b + 64;
  int lo = q0 - HALFW; if (lo < 0) lo = 0; lo &= ~31;
  int hi = q0 + 32 + HALFW; if (hi > S_LEN) hi = S_LEN;
  for (int c0 = lo; c0 < hi; c0 += 32) {
    f32x4 s[2][2] = {};   // [qg][kt]
    __builtin_amdgcn_s_setprio(1);
#pragma unroll
    for (int kt = 0; kt < 2; ++kt)
#pragma unroll
      for (int dh = 0; dh < 2; ++dh) {
        bfrag kf = *reinterpret_cast<const bfrag*>(&Kb[(size_t)(c0 + kt * 16 + col) * HD + 32 * dh + 8 * g]);
        s[0][kt] = __builtin_amdgcn_mfma_f32_16x16x32_bf16(kf, qf[0][dh], s[0][kt], 0, 0, 0);
        s[1][kt] = __builtin_amdgcn_mfma_f32_16x16x32_bf16(kf, qf[1][dh], s[1][kt], 0, 0, 0);
      }
    __builtin_amdgcn_s_setprio(0);
    bool full = (c0 >= q0 + 31 - HALFW) && (c0 + 31 <= q0 + HALFW);
    union { bfrag f; u32 w[4]; } pb[2];
#pragma unroll
    for (int qg = 0; qg < 2; ++qg) {
      float p0[4], p1[4];
      if (full) {
#pragma unroll
        for (int r = 0; r < 4; ++r) { p0[r] = fexp(s[qg][0][r]); p1[r] = fexp(s[qg][1][r]); }
      } else {
        int d0 = c0 + 4 * g - qi[qg] + HALFW;
#pragma unroll
        for (int r = 0; r < 4; ++r) {
          p0[r] = ((u32)(d0 + r) <= 2u * HALFW) ? fexp(s[qg][0][r]) : 0.f;
          p1[r] = ((u32)(d0 + 16 + r) <= 2u * HALFW) ? fexp(s[qg][1][r]) : 0.f;
        }
      }
      lacc[qg] += ((p0[0] + p0[1]) + (p0[2] + p0[3])) + ((p1[0] + p1[1]) + (p1[2] + p1[3]));
      u32 pk0 = cvtpk(p0[0], p0[1]), pk1 = cvtpk(p0[2], p0[3]);
      u32 pk2 = cvtpk(p1[0], p1[1]), pk3 = cvtpk(p1[2], p1[3]);
      u32 a0 = (u32)__builtin_amdgcn_ds_bpermute(l0b, (int)pk0);
      u32 b0 = (u32)__builtin_amdgcn_ds_bpermute(l0b, (int)pk2);
      u32 a1 = (u32)__builtin_amdgcn_ds_bpermute(l0b, (int)pk1);
      u32 b1 = (u32)__builtin_amdgcn_ds_bpermute(l0b, (int)pk3);
      u32 a2 = (u32)__builtin_amdgcn_ds_bpermute(l1b, (int)pk0);
      u32 b2 = (u32)__builtin_amdgcn_ds_bpermute(l1b, (int)pk2);
      u32 a3 = (u32)__builtin_amdgcn_ds_bpermute(l1b, (int)pk1);
      u32 b3 = (u32)__builtin_amdgcn_ds_bpermute(l1b, (int)pk3);
      pb[qg].w[0] = hi5 ? b0 : a0;
      pb[qg].w[1] = hi5 ? b1 : a1;
      pb[qg].w[2] = hi5 ? b2 : a2;
      pb[qg].w[3] = hi5 ? b3 : a3;
    }
    __builtin_amdgcn_s_setprio(1);
#pragma unroll
    for (int n = 0; n < 4; ++n) {
      bfrag vf = *reinterpret_cast<const bfrag*>(&Vb[(size_t)(n * 16 + col) * S_LEN + c0 + 8 * g]);
      octx[0][n] = __builtin_amdgcn_mfma_f32_16x16x32_bf16(vf, pb[0].f, octx[0][n], 0, 0, 0);
      octx[1][n] = __builtin_amdgcn_mfma_f32_16x16x32_bf16(vf, pb[1].f, octx[1][n], 0, 0, 0);
    }
    __builtin_amdgcn_s_setprio(0);
  }
#pragma unroll
  for (int qg = 0; qg < 2; ++qg) {
    float l = lacc[qg] + __shfl_xor(lacc[qg], 16);
    l += __shfl_xor(l, 32);
    float linv = __builtin_amdgcn_rcpf(l);
    u16* cb = ctx + (size_t)b * S_LEN * DMODEL + (size_t)(q0 + qg * 16 + col) * DMODEL + h * HD;
#pragma unroll
    for (int n = 0; n < 4; ++n) {
      uint2 o;
      o.x = cvtpk(octx[qg][n][0] * linv, octx[qg][n][1] * linv);
      o.y = cvtpk(octx[qg][n][2] * linv, octx[qg][n][3] * linv);
      *reinterpret_cast<uint2*>(cb + n * 16 + 4 * g) = o;
    }
  }
}

extern "C" void kernel_launch(void* const* d_in, const int* in_sizes, int n_in,
                              void* d_out, int out_size, void* d_ws, size_t ws_size,
                              hipStream_t stream) {
  (void)in_sizes; (void)n_in; (void)out_size; (void)ws_size;
  const float* x  = (const float*)d_in[0];
  const float* Wq = (const float*)d_in[1];
  const float* Wk = (const float*)d_in[2];
  const float* Wv = (const float*)d_in[3];
  const float* Wo = (const float*)d_in[4];
  char* ws = (char*)d_ws;
  u16*    xb     = (u16*)(ws + 0);          //  8,388,608
  u16*    Wcat_t = (u16*)(ws + 8388608);    //  3,145,728  (1536 x 1024)
  u16*    Wo_t   = (u16*)(ws + 11534336);   //  2,097,152
  u16*    Qr     = (u16*)(ws + 13631488);   //  8,388,608  (b,h,s,64)
  u16*    Kr     = (u16*)(ws + 22020096);   //  2,097,152  (b,kv,s,64)
  u16*    Vt     = (u16*)(ws + 24117248);   //  2,097,152  (b,kv,64,s)
  u16*    ctxb   = (u16*)(ws + 26214400);   //  8,388,608
  float2* csT    = (float2*)(ws + 34603008);//    524,288  -> total 35,127,296 B

  prep_k<<<dim3(32, 216), dim3(32, 8), 0, stream>>>(x, Wq, Wk, Wv, Wo, xb, Wcat_t, Wo_t, csT);
  gemm_qkv_k<<<dim3(24, 32), 256, 0, stream>>>(xb, Wcat_t, csT, Qr, Kr, Vt);
  attn_k<<<512, 256, 0, stream>>>(Qr, Kr, Vt, ctxb);
  gemm_bt_k<<<dim3(16, 32), 256, 0, stream>>>(ctxb, Wo_t, (float*)d_out, 1024);
}